// Round 6
// baseline (530.230 us; speedup 1.0000x reference)
//
#include <hip/hip_runtime.h>

#define B_ 8
#define S_ 2048
#define DIN_ 1024
#define DOUT_ 1024

using bf16 = __bf16;
using bf16x4 = __attribute__((ext_vector_type(4))) bf16;
using bf16x8 = __attribute__((ext_vector_type(8))) bf16;
using f32x4  = __attribute__((ext_vector_type(4))) float;

// ---------------- elementwise / small kernels ----------------

__global__ __launch_bounds__(256) void cast_k(const float* __restrict__ in,
                                              bf16* __restrict__ out, long n) {
  long i = ((long)blockIdx.x * blockDim.x + threadIdx.x) * 4;
  long stride = (long)gridDim.x * blockDim.x * 4;
  for (; i < n; i += stride) {
    float4 v = *(const float4*)(in + i);
    bf16x4 o = { (bf16)v.x, (bf16)v.y, (bf16)v.z, (bf16)v.w };
    *(bf16x4*)(out + i) = o;
  }
}

// Wl [f,e] fp32 -> Wl_t [e,f] bf16  (1024x1024)
__global__ __launch_bounds__(1024) void transpose_cast_k(const float* __restrict__ in,
                                                         bf16* __restrict__ out) {
  __shared__ float tile[32][33];
  int x = blockIdx.x * 32 + threadIdx.x;  // e (input col)
  int y = blockIdx.y * 32 + threadIdx.y;  // f (input row)
  tile[threadIdx.y][threadIdx.x] = in[y * 1024 + x];
  __syncthreads();
  int xo = blockIdx.y * 32 + threadIdx.x; // f (output col)
  int yo = blockIdx.x * 32 + threadIdx.y; // e (output row)
  out[yo * 1024 + xo] = (bf16)tile[threadIdx.x][threadIdx.y];
}

// out[r] = sum_c W[r,c]*v[c]   (one wave per row)
__global__ __launch_bounds__(256) void rowdot_k(const float* __restrict__ W,
                                                const float* __restrict__ v,
                                                float* __restrict__ out, int cols) {
  int row = blockIdx.x * 4 + (threadIdx.x >> 6);
  int lane = threadIdx.x & 63;
  float s = 0.f;
  const float* p = W + (long)row * cols;
  for (int c = lane; c < cols; c += 64) s += p[c] * v[c];
#pragma unroll
  for (int o = 32; o; o >>= 1) s += __shfl_down(s, o);
  if (!lane) out[row] = s;
}

__global__ __launch_bounds__(256) void dot1_k(const float* __restrict__ a,
                                              const float* __restrict__ b,
                                              float* __restrict__ out, int n) {
  __shared__ float sm[256];
  float s = 0.f;
  for (int i = threadIdx.x; i < n; i += 256) s += a[i] * b[i];
  sm[threadIdx.x] = s;
  __syncthreads();
  for (int o = 128; o; o >>= 1) {
    if (threadIdx.x < o) sm[threadIdx.x] += sm[threadIdx.x + o];
    __syncthreads();
  }
  if (!threadIdx.x) out[0] = sm[0];
}

// c2[e] = sum_f bv[f]*Wl[f,e]
__global__ __launch_bounds__(256) void colmat_k(const float* __restrict__ Wl,
                                                const float* __restrict__ bv,
                                                float* __restrict__ c2) {
  int e = blockIdx.x * 256 + threadIdx.x;
  float s = 0.f;
  for (int f = 0; f < 1024; f++) s += bv[f] * Wl[f * 1024 + e];
  c2[e] = s;
}

// alpha[i] = xs_i . kb ; beta[i] = xs_i . qb    (one wave per row, B*S rows)
__global__ __launch_bounds__(256) void alphabeta_k(const float* __restrict__ xs,
                                                   const float* __restrict__ kb,
                                                   const float* __restrict__ qb,
                                                   float* __restrict__ al,
                                                   float* __restrict__ be) {
  int row = blockIdx.x * 4 + (threadIdx.x >> 6);
  int lane = threadIdx.x & 63;
  const float* x = xs + (long)row * DIN_;
  float sa = 0.f, sb = 0.f;
  for (int c = lane; c < DIN_; c += 64) {
    float xv = x[c];
    sa += xv * kb[c];
    sb += xv * qb[c];
  }
#pragma unroll
  for (int o = 32; o; o >>= 1) { sa += __shfl_down(sa, o); sb += __shfl_down(sb, o); }
  if (!lane) { al[row] = sa; be[row] = sb; }
}

// rowsum[b,i] = S*EPS + sum_j E[b,i,j]*mask[b,j]/csum[b,j]   (one wave per row)
__global__ __launch_bounds__(256) void rowsum_k(const bf16* __restrict__ E,
                                                const float* __restrict__ mask,
                                                const float* __restrict__ csum,
                                                float* __restrict__ rs) {
  int row = blockIdx.x * 4 + (threadIdx.x >> 6); // global row b*S+i
  int lane = threadIdx.x & 63;
  int b = row >> 11;
  const bf16* p = E + (long)row * S_;
  const float* mb = mask + b * S_;
  const float* cb = csum + b * S_;
  float s = 0.f;
  for (int j = lane * 4; j < S_; j += 256) {
    bf16x4 ev = *(const bf16x4*)(p + j);
    float4 mv = *(const float4*)(mb + j);
    float4 cv = *(const float4*)(cb + j);
    s += (float)ev[0] * mv.x / cv.x + (float)ev[1] * mv.y / cv.y +
         (float)ev[2] * mv.z / cv.z + (float)ev[3] * mv.w / cv.w;
  }
#pragma unroll
  for (int o = 32; o; o >>= 1) s += __shfl_down(s, o);
  if (!lane) rs[row] = s + 2.048e-11f; // S * EPS
}

// ---------------- MFMA GEMM: C = A[M,K] * B[N,K]^T ----------------
// m97 structure: 128x128 tile, BK=32, 4 waves (2x2 of 64x64), global_load_lds w=16.
// EPI 0: store bf16 C
// EPI 1: E = exp((acc + alpha_i + beta_j + gamma)/1024), store bf16,
//        + fused column-sum partials atomicAdd'ed into e3[b*N + col]
// EPI 2: out = leakyrelu(rs_i*(acc + c2_j) + bl_j), store fp32

__device__ __forceinline__ void gld16(const bf16* g, bf16* l) {
  __builtin_amdgcn_global_load_lds(
      (__attribute__((address_space(1))) void*)const_cast<bf16*>(g),
      (__attribute__((address_space(3))) void*)l, 16, 0, 0);
}

template <int EPI>
__global__ __launch_bounds__(256) void gemm_bt(
    const bf16* __restrict__ A, const bf16* __restrict__ B,
    int M, int N, int K, long sA, long sB, long sC, void* __restrict__ C,
    const float* __restrict__ e0, const float* __restrict__ e1,
    const float* __restrict__ e2, float* __restrict__ e3) {
  __shared__ __align__(16) bf16 As[128 * 32];
  __shared__ __align__(16) bf16 Bs[128 * 32];
  const int tid = threadIdx.x;
  const int wid = tid >> 6, lane = tid & 63;
  const int z = blockIdx.z;
  A += (long)z * sA;
  B += (long)z * sB;
  const int bm0 = blockIdx.y * 128, bn0 = blockIdx.x * 128;
  const int mb = (wid >> 1) * 64, nb = (wid & 1) * 64;
  const int fr = lane & 15, ko = (lane >> 4) * 8;

  f32x4 acc[4][4] = {};

  const int srow = wid * 32 + (lane >> 2);
  const int scol = (lane & 3) * 8;
  const bf16* gA = A + (long)(bm0 + srow) * K + scol;
  const bf16* gB = B + (long)(bn0 + srow) * K + scol;
  bf16* lA = As + wid * 32 * 32;
  bf16* lB = Bs + wid * 32 * 32;

  for (int k0 = 0; k0 < K; k0 += 32) {
    gld16(gA + k0, lA);
    gld16(gA + 16 * K + k0, lA + 16 * 32);
    gld16(gB + k0, lB);
    gld16(gB + 16 * K + k0, lB + 16 * 32);
    __syncthreads();
    bf16x8 af[4], bfr[4];
#pragma unroll
    for (int m = 0; m < 4; m++)
      af[m] = *(const bf16x8*)(As + (mb + m * 16 + fr) * 32 + ko);
#pragma unroll
    for (int n = 0; n < 4; n++)
      bfr[n] = *(const bf16x8*)(Bs + (nb + n * 16 + fr) * 32 + ko);
#pragma unroll
    for (int m = 0; m < 4; m++)
#pragma unroll
      for (int n = 0; n < 4; n++)
        acc[m][n] = __builtin_amdgcn_mfma_f32_16x16x32_bf16(af[m], bfr[n], acc[m][n], 0, 0, 0);
    __syncthreads();
  }

  const int ci = (lane >> 4) * 4;
  const int cj = fr;
  if constexpr (EPI == 0 || EPI == 1) {
    bf16* Cp = (bf16*)C + (long)z * sC;
    float gam = (EPI == 1) ? e2[0] : 0.f;
    float colp[4] = {0.f, 0.f, 0.f, 0.f};
#pragma unroll
    for (int m = 0; m < 4; m++) {
      const int rb = bm0 + mb + m * 16 + ci;
#pragma unroll
      for (int n = 0; n < 4; n++) {
        const int cb = bn0 + nb + n * 16 + cj;
#pragma unroll
        for (int r = 0; r < 4; r++) {
          float v = acc[m][n][r];
          if constexpr (EPI == 1) {
            v = __expf((v + e0[z * M + rb + r] + e1[z * N + cb] + gam) * (1.f / 1024.f));
            colp[n] += v;
          }
          Cp[(long)(rb + r) * N + cb] = (bf16)v;
        }
      }
    }
    if constexpr (EPI == 1) {
      // lanes l, l^16, l^32, l^48 hold the same column (cj=lane&15) for the
      // 4 row-groups; butterfly-reduce then one atomicAdd per column per wave.
#pragma unroll
      for (int n = 0; n < 4; n++) {
        float s = colp[n];
        s += __shfl_xor(s, 16);
        s += __shfl_xor(s, 32);
        if (lane < 16)
          atomicAdd(&e3[(long)z * N + bn0 + nb + n * 16 + cj], s);
      }
    }
  } else {
    float* Cp = (float*)C;
#pragma unroll
    for (int m = 0; m < 4; m++) {
      const int rb = bm0 + mb + m * 16 + ci;
#pragma unroll
      for (int n = 0; n < 4; n++) {
        const int cb = bn0 + nb + n * 16 + cj;
#pragma unroll
        for (int r = 0; r < 4; r++) {
          float v = e0[rb + r] * (acc[m][n][r] + e1[cb]) + e2[cb];
          v = v < 0.f ? 0.01f * v : v;
          Cp[(long)(rb + r) * N + cb] = v;
        }
      }
    }
  }
}

// ---------------- launch ----------------

extern "C" void kernel_launch(void* const* d_in, const int* in_sizes, int n_in,
                              void* d_out, int out_size, void* d_ws, size_t ws_size,
                              hipStream_t stream) {
  const float* xs   = (const float*)d_in[0];
  const float* mask = (const float*)d_in[1];
  const float* Wk   = (const float*)d_in[2];
  const float* bk   = (const float*)d_in[3];
  const float* Wq   = (const float*)d_in[4];
  const float* bq   = (const float*)d_in[5];
  const float* Wv   = (const float*)d_in[6];
  const float* bv   = (const float*)d_in[7];
  const float* Wl   = (const float*)d_in[8];
  const float* bl   = (const float*)d_in[9];
  float* out = (float*)d_out;

  char* ws = (char*)d_ws;
  size_t off = 0;
  auto alloc = [&](size_t bytes) -> void* {
    void* p = ws + off;
    off += (bytes + 255) & ~(size_t)255;
    return p;
  };
  bf16* xs_bf = (bf16*)alloc((size_t)B_ * S_ * DIN_ * 2);   // 32MB
  bf16* t_bf  = (bf16*)alloc((size_t)B_ * S_ * DOUT_ * 2);  // 32MB
  bf16* Wk_bf = (bf16*)alloc((size_t)DIN_ * DOUT_ * 2);
  bf16* Wq_bf = (bf16*)alloc((size_t)DIN_ * DOUT_ * 2);
  bf16* Wv_bf = (bf16*)alloc((size_t)DIN_ * DOUT_ * 2);
  bf16* Wl_t  = (bf16*)alloc((size_t)DIN_ * DOUT_ * 2);
  bf16* Mt    = (bf16*)alloc((size_t)DIN_ * DOUT_ * 2);
  bf16* W2t   = (bf16*)alloc((size_t)DIN_ * DOUT_ * 2);
  float* kb    = (float*)alloc(DIN_ * 4);
  float* qb    = (float*)alloc(DIN_ * 4);
  float* c2    = (float*)alloc(DOUT_ * 4);
  float* gma   = (float*)alloc(256);
  float* alpha = (float*)alloc((size_t)B_ * S_ * 4);
  float* beta  = (float*)alloc((size_t)B_ * S_ * 4);
  float* csum  = (float*)alloc((size_t)B_ * S_ * 4);
  float* rs    = (float*)alloc((size_t)B_ * S_ * 4);
  size_t Eb = (size_t)B_ * S_ * S_ * 2; // 64MB
  bf16* E = (off + Eb <= ws_size) ? (bf16*)alloc(Eb) : (bf16*)d_out; // d_out is exactly 64MB and dead until final GEMM

  // casts
  cast_k<<<4096, 256, 0, stream>>>(xs, xs_bf, (long)B_ * S_ * DIN_);
  cast_k<<<1024, 256, 0, stream>>>(Wk, Wk_bf, (long)DIN_ * DOUT_);
  cast_k<<<1024, 256, 0, stream>>>(Wq, Wq_bf, (long)DIN_ * DOUT_);
  cast_k<<<1024, 256, 0, stream>>>(Wv, Wv_bf, (long)DIN_ * DOUT_);
  transpose_cast_k<<<dim3(32, 32), dim3(32, 32), 0, stream>>>(Wl, Wl_t);

  // bias folds (all zero with this data, but computed for correctness)
  rowdot_k<<<256, 256, 0, stream>>>(Wk, bq, kb, DOUT_);
  rowdot_k<<<256, 256, 0, stream>>>(Wq, bk, qb, DOUT_);
  dot1_k<<<1, 256, 0, stream>>>(bk, bq, gma, DOUT_);
  colmat_k<<<4, 256, 0, stream>>>(Wl, bv, c2);
  alphabeta_k<<<4096, 256, 0, stream>>>(xs, kb, qb, alpha, beta);

  // Mt[e,d] = sum_f Wq[e,f]*Wk[d,f]  (= (Wk Wq^T)^T)
  gemm_bt<0><<<dim3(8, 8, 1), 256, 0, stream>>>(Wq_bf, Wk_bf, 1024, 1024, 1024,
                                                0, 0, 0, Mt, nullptr, nullptr, nullptr, nullptr);
  // W2t[e,d] = sum_f Wl_t[e,f]*Wv[d,f] (= (Wv Wl)^T)
  gemm_bt<0><<<dim3(8, 8, 1), 256, 0, stream>>>(Wl_t, Wv_bf, 1024, 1024, 1024,
                                                0, 0, 0, W2t, nullptr, nullptr, nullptr, nullptr);
  // t[i,e] = sum_d xs[i,d]*Mt[e,d]
  gemm_bt<0><<<dim3(8, 128, 1), 256, 0, stream>>>(xs_bf, Mt, B_ * S_, 1024, 1024,
                                                  0, 0, 0, t_bf, nullptr, nullptr, nullptr, nullptr);
  // csum must be zero before the E-GEMM's fused column-sum atomics
  hipMemsetAsync(csum, 0, (size_t)B_ * S_ * 4, stream);
  // E[b,i,j] = exp((t_i . xs_j + alpha_i + beta_j + gamma)/1024), batched over b
  // + fused colsum into csum
  gemm_bt<1><<<dim3(16, 16, 8), 256, 0, stream>>>(t_bf, xs_bf, S_, S_, 1024,
                                                  (long)S_ * DIN_, (long)S_ * DIN_,
                                                  (long)S_ * S_, E, alpha, beta, gma, csum);
  // rowsum (w = mask/csum fused inline)
  rowsum_k<<<4096, 256, 0, stream>>>(E, mask, csum, rs);
  // out = leakyrelu(rs_i*(xs_i . W2t_e + c2_e) + bl_e)
  gemm_bt<2><<<dim3(8, 128, 1), 256, 0, stream>>>(xs_bf, W2t, B_ * S_, 1024, 1024,
                                                  0, 0, 0, out, rs, c2, bl, nullptr);
}

// Round 7
// 487.991 us; speedup vs baseline: 1.0866x; 1.0866x over previous
//
#include <hip/hip_runtime.h>

#define B_ 8
#define S_ 2048
#define DIN_ 1024
#define DOUT_ 1024

using bf16 = __bf16;
using bf16x4 = __attribute__((ext_vector_type(4))) bf16;
using bf16x8 = __attribute__((ext_vector_type(8))) bf16;
using f32x4  = __attribute__((ext_vector_type(4))) float;

// ---------------- elementwise / small kernels ----------------

__global__ __launch_bounds__(256) void cast_k(const float* __restrict__ in,
                                              bf16* __restrict__ out, long n) {
  long i = ((long)blockIdx.x * blockDim.x + threadIdx.x) * 4;
  long stride = (long)gridDim.x * blockDim.x * 4;
  for (; i < n; i += stride) {
    float4 v = *(const float4*)(in + i);
    bf16x4 o = { (bf16)v.x, (bf16)v.y, (bf16)v.z, (bf16)v.w };
    *(bf16x4*)(out + i) = o;
  }
}

// Wl [f,e] fp32 -> Wl_t [e,f] bf16  (1024x1024)
__global__ __launch_bounds__(1024) void transpose_cast_k(const float* __restrict__ in,
                                                         bf16* __restrict__ out) {
  __shared__ float tile[32][33];
  int x = blockIdx.x * 32 + threadIdx.x;  // e (input col)
  int y = blockIdx.y * 32 + threadIdx.y;  // f (input row)
  tile[threadIdx.y][threadIdx.x] = in[y * 1024 + x];
  __syncthreads();
  int xo = blockIdx.y * 32 + threadIdx.x; // f (output col)
  int yo = blockIdx.x * 32 + threadIdx.y; // e (output row)
  out[yo * 1024 + xo] = (bf16)tile[threadIdx.x][threadIdx.y];
}

// out[r] = sum_c W[r,c]*v[c]   (one wave per row)
__global__ __launch_bounds__(256) void rowdot_k(const float* __restrict__ W,
                                                const float* __restrict__ v,
                                                float* __restrict__ out, int cols) {
  int row = blockIdx.x * 4 + (threadIdx.x >> 6);
  int lane = threadIdx.x & 63;
  float s = 0.f;
  const float* p = W + (long)row * cols;
  for (int c = lane; c < cols; c += 64) s += p[c] * v[c];
#pragma unroll
  for (int o = 32; o; o >>= 1) s += __shfl_down(s, o);
  if (!lane) out[row] = s;
}

__global__ __launch_bounds__(256) void dot1_k(const float* __restrict__ a,
                                              const float* __restrict__ b,
                                              float* __restrict__ out, int n) {
  __shared__ float sm[256];
  float s = 0.f;
  for (int i = threadIdx.x; i < n; i += 256) s += a[i] * b[i];
  sm[threadIdx.x] = s;
  __syncthreads();
  for (int o = 128; o; o >>= 1) {
    if (threadIdx.x < o) sm[threadIdx.x] += sm[threadIdx.x + o];
    __syncthreads();
  }
  if (!threadIdx.x) out[0] = sm[0];
}

// c2[e] = sum_f bv[f]*Wl[f,e]
__global__ __launch_bounds__(256) void colmat_k(const float* __restrict__ Wl,
                                                const float* __restrict__ bv,
                                                float* __restrict__ c2) {
  int e = blockIdx.x * 256 + threadIdx.x;
  float s = 0.f;
  for (int f = 0; f < 1024; f++) s += bv[f] * Wl[f * 1024 + e];
  c2[e] = s;
}

// alpha[i] = xs_i . kb ; beta[i] = xs_i . qb    (one wave per row, B*S rows)
__global__ __launch_bounds__(256) void alphabeta_k(const float* __restrict__ xs,
                                                   const float* __restrict__ kb,
                                                   const float* __restrict__ qb,
                                                   float* __restrict__ al,
                                                   float* __restrict__ be) {
  int row = blockIdx.x * 4 + (threadIdx.x >> 6);
  int lane = threadIdx.x & 63;
  const float* x = xs + (long)row * DIN_;
  float sa = 0.f, sb = 0.f;
  for (int c = lane; c < DIN_; c += 64) {
    float xv = x[c];
    sa += xv * kb[c];
    sb += xv * qb[c];
  }
#pragma unroll
  for (int o = 32; o; o >>= 1) { sa += __shfl_down(sa, o); sb += __shfl_down(sb, o); }
  if (!lane) { al[row] = sa; be[row] = sb; }
}

// rowsum[b,i] = S*EPS + sum_j E[b,i,j]*mask[b,j]/csum[b,j]   (one wave per row)
__global__ __launch_bounds__(256) void rowsum_k(const bf16* __restrict__ E,
                                                const float* __restrict__ mask,
                                                const float* __restrict__ csum,
                                                float* __restrict__ rs) {
  int row = blockIdx.x * 4 + (threadIdx.x >> 6); // global row b*S+i
  int lane = threadIdx.x & 63;
  int b = row >> 11;
  const bf16* p = E + (long)row * S_;
  const float* mb = mask + b * S_;
  const float* cb = csum + b * S_;
  float s = 0.f;
  for (int j = lane * 4; j < S_; j += 256) {
    bf16x4 ev = *(const bf16x4*)(p + j);
    float4 mv = *(const float4*)(mb + j);
    float4 cv = *(const float4*)(cb + j);
    s += (float)ev[0] * mv.x / cv.x + (float)ev[1] * mv.y / cv.y +
         (float)ev[2] * mv.z / cv.z + (float)ev[3] * mv.w / cv.w;
  }
#pragma unroll
  for (int o = 32; o; o >>= 1) s += __shfl_down(s, o);
  if (!lane) rs[row] = s + 2.048e-11f; // S * EPS
}

__device__ __forceinline__ void gld16(const bf16* g, bf16* l) {
  __builtin_amdgcn_global_load_lds(
      (__attribute__((address_space(1))) void*)const_cast<bf16*>(g),
      (__attribute__((address_space(3))) void*)l, 16, 0, 0);
}

// ---------------- small MFMA GEMM (m97 structure), for 1024^3 only ----------
__global__ __launch_bounds__(256) void gemm_bt(
    const bf16* __restrict__ A, const bf16* __restrict__ B,
    int M, int N, int K, void* __restrict__ C) {
  __shared__ __align__(16) bf16 As[128 * 32];
  __shared__ __align__(16) bf16 Bs[128 * 32];
  const int tid = threadIdx.x;
  const int wid = tid >> 6, lane = tid & 63;
  const int bm0 = blockIdx.y * 128, bn0 = blockIdx.x * 128;
  const int mb = (wid >> 1) * 64, nb = (wid & 1) * 64;
  const int fr = lane & 15, ko = (lane >> 4) * 8;

  f32x4 acc[4][4] = {};

  const int srow = wid * 32 + (lane >> 2);
  const int scol = (lane & 3) * 8;
  const bf16* gA = A + (long)(bm0 + srow) * K + scol;
  const bf16* gB = B + (long)(bn0 + srow) * K + scol;
  bf16* lA = As + wid * 32 * 32;
  bf16* lB = Bs + wid * 32 * 32;

  for (int k0 = 0; k0 < K; k0 += 32) {
    gld16(gA + k0, lA);
    gld16(gA + 16 * K + k0, lA + 16 * 32);
    gld16(gB + k0, lB);
    gld16(gB + 16 * K + k0, lB + 16 * 32);
    __syncthreads();
    bf16x8 af[4], bfr[4];
#pragma unroll
    for (int m = 0; m < 4; m++)
      af[m] = *(const bf16x8*)(As + (mb + m * 16 + fr) * 32 + ko);
#pragma unroll
    for (int n = 0; n < 4; n++)
      bfr[n] = *(const bf16x8*)(Bs + (nb + n * 16 + fr) * 32 + ko);
#pragma unroll
    for (int m = 0; m < 4; m++)
#pragma unroll
      for (int n = 0; n < 4; n++)
        acc[m][n] = __builtin_amdgcn_mfma_f32_16x16x32_bf16(af[m], bfr[n], acc[m][n], 0, 0, 0);
    __syncthreads();
  }

  const int ci = (lane >> 4) * 4;
  bf16* Cp = (bf16*)C;
#pragma unroll
  for (int m = 0; m < 4; m++) {
    const int rb = bm0 + mb + m * 16 + ci;
#pragma unroll
    for (int n = 0; n < 4; n++) {
      const int cb = bn0 + nb + n * 16 + fr;
#pragma unroll
      for (int r = 0; r < 4; r++)
        Cp[(long)(rb + r) * N + cb] = (bf16)acc[m][n][r];
    }
  }
}

// ---------------- big MFMA GEMM: C = A[M,K] * B[N,K]^T -----------------------
// 3-buffer pipelined structure: BM=256, BN=128, BK=64, 8 waves (4M x 2N),
// LDS 3 x 48KB. Counted vmcnt: at iter t issue tile t+2's loads (6/wave),
// end-of-iter waits vmcnt(6) -> drains exactly tile t+1's loads, leaving
// t+2's in flight. T2 XOR-swizzle (seg ^= row&7) with pre-swizzled global
// source (linear LDS dest, swizzled ds_read). setprio around MFMA clusters.
// EPI 0: store bf16 C
// EPI 1: E = exp((acc + e0_i + e1_j + e2[0])/1024), store bf16, colsum -> e3
// EPI 2: out = leakyrelu(e0_i*(acc + e1_j) + e2_j), store fp32

template <int EPI>
__global__ __launch_bounds__(512, 1) void gemm3(
    const bf16* __restrict__ A, const bf16* __restrict__ B,
    int M, int N, int K, long sA, long sB, long sC, void* __restrict__ C,
    const float* __restrict__ e0, const float* __restrict__ e1,
    const float* __restrict__ e2, float* __restrict__ e3) {
  __shared__ __align__(16) bf16 sm[3 * 24576]; // 3 x (A 256x64 + B 128x64) = 144KB
  const int tid = threadIdx.x;
  const int wid = tid >> 6, lane = tid & 63;
  const int z = blockIdx.z;
  A += (long)z * sA;
  B += (long)z * sB;
  const int bm0 = blockIdx.y * 256, bn0 = blockIdx.x * 128;
  const int wm = wid >> 1, wn = wid & 1;
  const int NT = K >> 6;

  // staging: per K-tile each thread does 4 A-loads + 2 B-loads (16B each).
  // chunk = 1KB = 8 rows x 64 cols; lane covers row (lane>>3), seg (lane&7)
  // of linear LDS; global seg pre-swizzled by ^(row&7) so that swizzled
  // reads (seg ^ row&7) recover linear k.
  const int lrow = lane >> 3;
  const int lseg = (lane & 7) ^ lrow;
  const bf16* gA = A + (long)(bm0 + wid * 32 + lrow) * K + lseg * 8;
  const bf16* gB = B + (long)(bn0 + wid * 16 + lrow) * K + lseg * 8;

  f32x4 acc[4][4] = {};

  auto STAGE = [&](int buf, int t) {
    bf16* lA = sm + buf * 24576 + wid * 2048;
    bf16* lB = sm + buf * 24576 + 16384 + wid * 1024;
    const bf16* ga = gA + t * 64;
    const bf16* gb = gB + t * 64;
#pragma unroll
    for (int l = 0; l < 4; l++) gld16(ga + (long)l * 8 * K, lA + l * 512);
#pragma unroll
    for (int l = 0; l < 2; l++) gld16(gb + (long)l * 8 * K, lB + l * 512);
  };

  STAGE(0, 0);
  if (NT > 1) STAGE(1, 1);
  asm volatile("s_waitcnt vmcnt(6)" ::: "memory"); // drain tile0's 6, leave tile1's
  __builtin_amdgcn_s_barrier();

  const int fr = lane & 15;
  const int rowA0 = wm * 64 + fr;
  const int rowB0 = wn * 64 + fr;
  const int seg0 = lane >> 4;

  for (int t = 0; t < NT; ++t) {
    const bf16* Ab = sm + (t % 3) * 24576;
    const bf16* Bb = Ab + 16384;
    if (t + 2 < NT) STAGE((t + 2) % 3, t + 2);
#pragma unroll
    for (int kh = 0; kh < 2; kh++) {
      bf16x8 a[4], b[4];
#pragma unroll
      for (int m = 0; m < 4; m++) {
        const int row = rowA0 + m * 16;
        const int s = (seg0 + 4 * kh) ^ (row & 7);
        a[m] = *(const bf16x8*)(Ab + row * 64 + s * 8);
      }
#pragma unroll
      for (int n = 0; n < 4; n++) {
        const int row = rowB0 + n * 16;
        const int s = (seg0 + 4 * kh) ^ (row & 7);
        b[n] = *(const bf16x8*)(Bb + row * 64 + s * 8);
      }
      __builtin_amdgcn_s_setprio(1);
#pragma unroll
      for (int m = 0; m < 4; m++)
#pragma unroll
        for (int n = 0; n < 4; n++)
          acc[m][n] = __builtin_amdgcn_mfma_f32_16x16x32_bf16(a[m], b[n], acc[m][n], 0, 0, 0);
      __builtin_amdgcn_s_setprio(0);
    }
    if (t < NT - 1) {
      // outstanding: S(t+1) [6, oldest] + S(t+2) [6 if issued]. Drain t+1's.
      if (t + 2 < NT) asm volatile("s_waitcnt vmcnt(6)" ::: "memory");
      else            asm volatile("s_waitcnt vmcnt(0)" ::: "memory");
      __builtin_amdgcn_s_barrier();
    }
  }

  const int ci = (lane >> 4) * 4;
  const int cj = fr;
  if constexpr (EPI == 0 || EPI == 1) {
    bf16* Cp = (bf16*)C + (long)z * sC;
    float gam = (EPI == 1) ? e2[0] : 0.f;
    float colp[4] = {0.f, 0.f, 0.f, 0.f};
#pragma unroll
    for (int m = 0; m < 4; m++) {
      const int rb = bm0 + wm * 64 + m * 16 + ci;
#pragma unroll
      for (int n = 0; n < 4; n++) {
        const int cb = bn0 + wn * 64 + n * 16 + cj;
#pragma unroll
        for (int r = 0; r < 4; r++) {
          float v = acc[m][n][r];
          if constexpr (EPI == 1) {
            v = __expf((v + e0[z * M + rb + r] + e1[z * N + cb] + gam) * (1.f / 1024.f));
            colp[n] += v;
          }
          Cp[(long)(rb + r) * N + cb] = (bf16)v;
        }
      }
    }
    if constexpr (EPI == 1) {
      // lanes l, l^16, l^32, l^48 share column cj across the 4 row-groups of
      // this wave's 64-row tile; butterfly then one atomicAdd per column.
#pragma unroll
      for (int n = 0; n < 4; n++) {
        float s = colp[n];
        s += __shfl_xor(s, 16);
        s += __shfl_xor(s, 32);
        if (lane < 16)
          atomicAdd(&e3[(long)z * N + bn0 + wn * 64 + n * 16 + cj], s);
      }
    }
  } else {
    float* Cp = (float*)C;
#pragma unroll
    for (int m = 0; m < 4; m++) {
      const int rb = bm0 + wm * 64 + m * 16 + ci;
#pragma unroll
      for (int n = 0; n < 4; n++) {
        const int cb = bn0 + wn * 64 + n * 16 + cj;
#pragma unroll
        for (int r = 0; r < 4; r++) {
          float v = e0[rb + r] * (acc[m][n][r] + e1[cb]) + e2[cb];
          v = v < 0.f ? 0.01f * v : v;
          Cp[(long)(rb + r) * N + cb] = v;
        }
      }
    }
  }
}

// ---------------- launch ----------------

extern "C" void kernel_launch(void* const* d_in, const int* in_sizes, int n_in,
                              void* d_out, int out_size, void* d_ws, size_t ws_size,
                              hipStream_t stream) {
  const float* xs   = (const float*)d_in[0];
  const float* mask = (const float*)d_in[1];
  const float* Wk   = (const float*)d_in[2];
  const float* bk   = (const float*)d_in[3];
  const float* Wq   = (const float*)d_in[4];
  const float* bq   = (const float*)d_in[5];
  const float* Wv   = (const float*)d_in[6];
  const float* bv   = (const float*)d_in[7];
  const float* Wl   = (const float*)d_in[8];
  const float* bl   = (const float*)d_in[9];
  float* out = (float*)d_out;

  char* ws = (char*)d_ws;
  size_t off = 0;
  auto alloc = [&](size_t bytes) -> void* {
    void* p = ws + off;
    off += (bytes + 255) & ~(size_t)255;
    return p;
  };
  bf16* xs_bf = (bf16*)alloc((size_t)B_ * S_ * DIN_ * 2);   // 32MB
  bf16* t_bf  = (bf16*)alloc((size_t)B_ * S_ * DOUT_ * 2);  // 32MB
  bf16* Wk_bf = (bf16*)alloc((size_t)DIN_ * DOUT_ * 2);
  bf16* Wq_bf = (bf16*)alloc((size_t)DIN_ * DOUT_ * 2);
  bf16* Wv_bf = (bf16*)alloc((size_t)DIN_ * DOUT_ * 2);
  bf16* Wl_t  = (bf16*)alloc((size_t)DIN_ * DOUT_ * 2);
  bf16* Mt    = (bf16*)alloc((size_t)DIN_ * DOUT_ * 2);
  bf16* W2t   = (bf16*)alloc((size_t)DIN_ * DOUT_ * 2);
  float* kb    = (float*)alloc(DIN_ * 4);
  float* qb    = (float*)alloc(DIN_ * 4);
  float* c2    = (float*)alloc(DOUT_ * 4);
  float* gma   = (float*)alloc(256);
  float* alpha = (float*)alloc((size_t)B_ * S_ * 4);
  float* beta  = (float*)alloc((size_t)B_ * S_ * 4);
  float* csum  = (float*)alloc((size_t)B_ * S_ * 4);
  float* rs    = (float*)alloc((size_t)B_ * S_ * 4);
  size_t Eb = (size_t)B_ * S_ * S_ * 2; // 64MB
  bf16* E = (off + Eb <= ws_size) ? (bf16*)alloc(Eb) : (bf16*)d_out; // d_out dead until final GEMM

  // casts
  cast_k<<<4096, 256, 0, stream>>>(xs, xs_bf, (long)B_ * S_ * DIN_);
  cast_k<<<1024, 256, 0, stream>>>(Wk, Wk_bf, (long)DIN_ * DOUT_);
  cast_k<<<1024, 256, 0, stream>>>(Wq, Wq_bf, (long)DIN_ * DOUT_);
  cast_k<<<1024, 256, 0, stream>>>(Wv, Wv_bf, (long)DIN_ * DOUT_);
  transpose_cast_k<<<dim3(32, 32), dim3(32, 32), 0, stream>>>(Wl, Wl_t);

  // bias folds (all zero with this data, but computed for correctness)
  rowdot_k<<<256, 256, 0, stream>>>(Wk, bq, kb, DOUT_);
  rowdot_k<<<256, 256, 0, stream>>>(Wq, bk, qb, DOUT_);
  dot1_k<<<1, 256, 0, stream>>>(bk, bq, gma, DOUT_);
  colmat_k<<<4, 256, 0, stream>>>(Wl, bv, c2);
  alphabeta_k<<<4096, 256, 0, stream>>>(xs, kb, qb, alpha, beta);

  // Mt[e,d] = sum_f Wq[e,f]*Wk[d,f]  (= (Wk Wq^T)^T)
  gemm_bt<<<dim3(8, 8, 1), 256, 0, stream>>>(Wq_bf, Wk_bf, 1024, 1024, 1024, Mt);
  // W2t[e,d] = sum_f Wl_t[e,f]*Wv[d,f] (= (Wv Wl)^T)
  gemm_bt<<<dim3(8, 8, 1), 256, 0, stream>>>(Wl_t, Wv_bf, 1024, 1024, 1024, W2t);
  // t[i,e] = sum_d xs[i,d]*Mt[e,d]
  gemm3<0><<<dim3(8, 64, 1), 512, 0, stream>>>(xs_bf, Mt, B_ * S_, 1024, 1024,
                                               0, 0, 0, t_bf, nullptr, nullptr, nullptr, nullptr);
  // csum must be zero before the E-GEMM's fused column-sum atomics
  hipMemsetAsync(csum, 0, (size_t)B_ * S_ * 4, stream);
  // E[b,i,j] = exp((t_i . xs_j + alpha_i + beta_j + gamma)/1024) + fused colsum
  gemm3<1><<<dim3(16, 8, 8), 512, 0, stream>>>(t_bf, xs_bf, S_, S_, 1024,
                                               (long)S_ * DIN_, (long)S_ * DIN_,
                                               (long)S_ * S_, E, alpha, beta, gma, csum);
  // rowsum (w = mask/csum fused inline)
  rowsum_k<<<4096, 256, 0, stream>>>(E, mask, csum, rs);
  // out = leakyrelu(rs_i*(xs_i . W2t_e + c2_e) + bl_e)
  gemm3<2><<<dim3(8, 64, 1), 512, 0, stream>>>(xs_bf, W2t, B_ * S_, 1024, 1024,
                                               0, 0, 0, out, rs, c2, bl, nullptr);
}

// Round 8
// 399.996 us; speedup vs baseline: 1.3256x; 1.2200x over previous
//
#include <hip/hip_runtime.h>

#define B_ 8
#define S_ 2048
#define DIN_ 1024
#define DOUT_ 1024

using bf16 = __bf16;
using bf16x4 = __attribute__((ext_vector_type(4))) bf16;
using bf16x8 = __attribute__((ext_vector_type(8))) bf16;
using f32x4  = __attribute__((ext_vector_type(4))) float;

// ---------------- elementwise / small kernels ----------------

__global__ __launch_bounds__(256) void cast_k(const float* __restrict__ in,
                                              bf16* __restrict__ out, long n) {
  long i = ((long)blockIdx.x * blockDim.x + threadIdx.x) * 4;
  long stride = (long)gridDim.x * blockDim.x * 4;
  for (; i < n; i += stride) {
    float4 v = *(const float4*)(in + i);
    bf16x4 o = { (bf16)v.x, (bf16)v.y, (bf16)v.z, (bf16)v.w };
    *(bf16x4*)(out + i) = o;
  }
}

// Wl [f,e] fp32 -> Wl_t [e,f] bf16  (1024x1024)
__global__ __launch_bounds__(1024) void transpose_cast_k(const float* __restrict__ in,
                                                         bf16* __restrict__ out) {
  __shared__ float tile[32][33];
  int x = blockIdx.x * 32 + threadIdx.x;  // e (input col)
  int y = blockIdx.y * 32 + threadIdx.y;  // f (input row)
  tile[threadIdx.y][threadIdx.x] = in[y * 1024 + x];
  __syncthreads();
  int xo = blockIdx.y * 32 + threadIdx.x; // f (output col)
  int yo = blockIdx.x * 32 + threadIdx.y; // e (output row)
  out[yo * 1024 + xo] = (bf16)tile[threadIdx.x][threadIdx.y];
}

// out[r] = sum_c W[r,c]*v[c]   (one wave per row)
__global__ __launch_bounds__(256) void rowdot_k(const float* __restrict__ W,
                                                const float* __restrict__ v,
                                                float* __restrict__ out, int cols) {
  int row = blockIdx.x * 4 + (threadIdx.x >> 6);
  int lane = threadIdx.x & 63;
  float s = 0.f;
  const float* p = W + (long)row * cols;
  for (int c = lane; c < cols; c += 64) s += p[c] * v[c];
#pragma unroll
  for (int o = 32; o; o >>= 1) s += __shfl_down(s, o);
  if (!lane) out[row] = s;
}

__global__ __launch_bounds__(256) void dot1_k(const float* __restrict__ a,
                                              const float* __restrict__ b,
                                              float* __restrict__ out, int n) {
  __shared__ float sm[256];
  float s = 0.f;
  for (int i = threadIdx.x; i < n; i += 256) s += a[i] * b[i];
  sm[threadIdx.x] = s;
  __syncthreads();
  for (int o = 128; o; o >>= 1) {
    if (threadIdx.x < o) sm[threadIdx.x] += sm[threadIdx.x + o];
    __syncthreads();
  }
  if (!threadIdx.x) out[0] = sm[0];
}

// c2[e] += sum_{f in block} bv[f]*Wl[f,e]   (parallel over f-slices; c2 pre-zeroed)
__global__ __launch_bounds__(256) void colmat_k(const float* __restrict__ Wl,
                                                const float* __restrict__ bv,
                                                float* __restrict__ c2) {
  int e = blockIdx.x * 256 + threadIdx.x;
  int f0 = blockIdx.y * 32;
  float s = 0.f;
#pragma unroll 8
  for (int f = f0; f < f0 + 32; f++) s += bv[f] * Wl[(long)f * 1024 + e];
  atomicAdd(&c2[e], s);
}

// alpha[i] = xs_i . kb ; beta[i] = xs_i . qb    (one wave per row, B*S rows)
__global__ __launch_bounds__(256) void alphabeta_k(const float* __restrict__ xs,
                                                   const float* __restrict__ kb,
                                                   const float* __restrict__ qb,
                                                   float* __restrict__ al,
                                                   float* __restrict__ be) {
  int row = blockIdx.x * 4 + (threadIdx.x >> 6);
  int lane = threadIdx.x & 63;
  const float* x = xs + (long)row * DIN_;
  float sa = 0.f, sb = 0.f;
  for (int c = lane; c < DIN_; c += 64) {
    float xv = x[c];
    sa += xv * kb[c];
    sb += xv * qb[c];
  }
#pragma unroll
  for (int o = 32; o; o >>= 1) { sa += __shfl_down(sa, o); sb += __shfl_down(sb, o); }
  if (!lane) { al[row] = sa; be[row] = sb; }
}

// rowsum[b,i] = S*EPS + sum_j E[b,i,j]*mask[b,j]/csum[b,j]   (one wave per row)
__global__ __launch_bounds__(256) void rowsum_k(const bf16* __restrict__ E,
                                                const float* __restrict__ mask,
                                                const float* __restrict__ csum,
                                                float* __restrict__ rs) {
  int row = blockIdx.x * 4 + (threadIdx.x >> 6); // global row b*S+i
  int lane = threadIdx.x & 63;
  int b = row >> 11;
  const bf16* p = E + (long)row * S_;
  const float* mb = mask + b * S_;
  const float* cb = csum + b * S_;
  float s = 0.f;
  for (int j = lane * 4; j < S_; j += 256) {
    bf16x4 ev = *(const bf16x4*)(p + j);
    float4 mv = *(const float4*)(mb + j);
    float4 cv = *(const float4*)(cb + j);
    s += (float)ev[0] * mv.x / cv.x + (float)ev[1] * mv.y / cv.y +
         (float)ev[2] * mv.z / cv.z + (float)ev[3] * mv.w / cv.w;
  }
#pragma unroll
  for (int o = 32; o; o >>= 1) s += __shfl_down(s, o);
  if (!lane) rs[row] = s + 2.048e-11f; // S * EPS
}

__device__ __forceinline__ void gld16(const bf16* g, bf16* l) {
  __builtin_amdgcn_global_load_lds(
      (__attribute__((address_space(1))) void*)const_cast<bf16*>(g),
      (__attribute__((address_space(3))) void*)l, 16, 0, 0);
}

// ---------------- small MFMA GEMM (m97 structure), for 1024^3 only ----------
__global__ __launch_bounds__(256) void gemm_bt(
    const bf16* __restrict__ A, const bf16* __restrict__ B,
    int M, int N, int K, void* __restrict__ C) {
  __shared__ __align__(16) bf16 As[128 * 32];
  __shared__ __align__(16) bf16 Bs[128 * 32];
  const int tid = threadIdx.x;
  const int wid = tid >> 6, lane = tid & 63;
  const int bm0 = blockIdx.y * 128, bn0 = blockIdx.x * 128;
  const int mb = (wid >> 1) * 64, nb = (wid & 1) * 64;
  const int fr = lane & 15, ko = (lane >> 4) * 8;

  f32x4 acc[4][4] = {};

  const int srow = wid * 32 + (lane >> 2);
  const int scol = (lane & 3) * 8;
  const bf16* gA = A + (long)(bm0 + srow) * K + scol;
  const bf16* gB = B + (long)(bn0 + srow) * K + scol;
  bf16* lA = As + wid * 32 * 32;
  bf16* lB = Bs + wid * 32 * 32;

  for (int k0 = 0; k0 < K; k0 += 32) {
    gld16(gA + k0, lA);
    gld16(gA + 16 * K + k0, lA + 16 * 32);
    gld16(gB + k0, lB);
    gld16(gB + 16 * K + k0, lB + 16 * 32);
    __syncthreads();
    bf16x8 af[4], bfr[4];
#pragma unroll
    for (int m = 0; m < 4; m++)
      af[m] = *(const bf16x8*)(As + (mb + m * 16 + fr) * 32 + ko);
#pragma unroll
    for (int n = 0; n < 4; n++)
      bfr[n] = *(const bf16x8*)(Bs + (nb + n * 16 + fr) * 32 + ko);
#pragma unroll
    for (int m = 0; m < 4; m++)
#pragma unroll
      for (int n = 0; n < 4; n++)
        acc[m][n] = __builtin_amdgcn_mfma_f32_16x16x32_bf16(af[m], bfr[n], acc[m][n], 0, 0, 0);
    __syncthreads();
  }

  const int ci = (lane >> 4) * 4;
  bf16* Cp = (bf16*)C;
#pragma unroll
  for (int m = 0; m < 4; m++) {
    const int rb = bm0 + mb + m * 16 + ci;
#pragma unroll
    for (int n = 0; n < 4; n++) {
      const int cb = bn0 + nb + n * 16 + fr;
#pragma unroll
      for (int r = 0; r < 4; r++)
        Cp[(long)(rb + r) * N + cb] = (bf16)acc[m][n][r];
    }
  }
}

// ---------------- big MFMA GEMM: C = A[M,K] * B[N,K]^T -----------------------
// BM=256, BN=256, BK=64, 8 waves (2M x 4N), per-wave C = 128x64.
// 2-buffer LDS (128KB). Stage t+1 issued BEFORE compute(t) so the 8 loads'
// HBM latency hides under ~800cy of MFMA+ds_read; __syncthreads() at iter end
// drains + flips. 8-seg XOR swizzle (seg ^= row&7) via pre-swizzled global
// source (linear LDS dest) -- bank-conflict-free reads (verified 0 in r7).
// EPI 0: store bf16 C
// EPI 1: E = exp((acc + e0_i + e1_j + e2[0])/1024), store bf16, colsum -> e3
// EPI 2: out = leakyrelu(e0_i*(acc + e1_j) + e2_j), store fp32

template <int EPI>
__global__ __launch_bounds__(512, 1) void gemm3(
    const bf16* __restrict__ A, const bf16* __restrict__ B,
    int M, int N, int K, long sA, long sB, long sC, void* __restrict__ C,
    const float* __restrict__ e0, const float* __restrict__ e1,
    const float* __restrict__ e2, float* __restrict__ e3) {
  __shared__ __align__(16) bf16 sm[2 * 32768]; // 2 x (A 256x64 + B 256x64) = 128KB
  const int tid = threadIdx.x;
  const int wid = tid >> 6, lane = tid & 63;
  const int z = blockIdx.z;
  A += (long)z * sA;
  B += (long)z * sB;
  const int bm0 = blockIdx.y * 256, bn0 = blockIdx.x * 256;
  const int wm = wid >> 2, wn = wid & 3;   // 2 x 4 waves, per-wave 128x64
  const int NT = K >> 6;

  // staging: wave w covers rows w*32..w*32+31 of both A and B tiles.
  // 4 loads each (8 rows per load). lane -> (lrow, lseg); global seg
  // pre-swizzled by ^lrow... swizzle key is (row&7) == lrow&7 == lrow (lrow<8).
  const int lrow = lane >> 3;            // 0..7
  const int lseg = (lane & 7) ^ lrow;    // pre-swizzled source segment
  const bf16* gA = A + (long)(bm0 + wid * 32 + lrow) * K + lseg * 8;
  const bf16* gB = B + (long)(bn0 + wid * 32 + lrow) * K + lseg * 8;

  f32x4 acc[8][4] = {};

  auto STAGE = [&](int buf, int t) {
    bf16* lA = sm + buf * 32768 + wid * 2048;
    bf16* lB = sm + buf * 32768 + 16384 + wid * 2048;
    const bf16* ga = gA + t * 64;
    const bf16* gb = gB + t * 64;
#pragma unroll
    for (int l = 0; l < 4; l++) gld16(ga + (long)l * 8 * K, lA + l * 512);
#pragma unroll
    for (int l = 0; l < 4; l++) gld16(gb + (long)l * 8 * K, lB + l * 512);
  };

  STAGE(0, 0);
  __syncthreads();   // drain tile0 (vmcnt0+lgkmcnt0+barrier)

  const int fr = lane & 15;
  const int seg0 = lane >> 4;            // 0..3

  for (int t = 0; t < NT; ++t) {
    const bf16* Ab = sm + (t & 1) * 32768;
    const bf16* Bb = Ab + 16384;
    if (t + 1 < NT) STAGE((t + 1) & 1, t + 1);  // issue early; hides under compute
#pragma unroll
    for (int kh = 0; kh < 2; kh++) {
      bf16x8 b[4];
#pragma unroll
      for (int n = 0; n < 4; n++) {
        const int row = wn * 64 + n * 16 + fr;
        const int s = (seg0 + 4 * kh) ^ (row & 7);
        b[n] = *(const bf16x8*)(Bb + row * 64 + s * 8);
      }
#pragma unroll
      for (int mh = 0; mh < 2; mh++) {
        bf16x8 a[4];
#pragma unroll
        for (int m = 0; m < 4; m++) {
          const int row = wm * 128 + mh * 64 + m * 16 + fr;
          const int s = (seg0 + 4 * kh) ^ (row & 7);
          a[m] = *(const bf16x8*)(Ab + row * 64 + s * 8);
        }
        __builtin_amdgcn_s_setprio(1);
#pragma unroll
        for (int m = 0; m < 4; m++)
#pragma unroll
          for (int n = 0; n < 4; n++)
            acc[mh * 4 + m][n] = __builtin_amdgcn_mfma_f32_16x16x32_bf16(a[m], b[n], acc[mh * 4 + m][n], 0, 0, 0);
        __builtin_amdgcn_s_setprio(0);
      }
    }
    if (t + 1 < NT) __syncthreads();  // drain t+1's stages + flip buffers
  }

  const int ci = (lane >> 4) * 4;
  const int cj = fr;
  if constexpr (EPI == 0 || EPI == 1) {
    bf16* Cp = (bf16*)C + (long)z * sC;
    float gam = (EPI == 1) ? e2[0] : 0.f;
    float colp[4] = {0.f, 0.f, 0.f, 0.f};
#pragma unroll
    for (int m = 0; m < 8; m++) {
      const int rb = bm0 + wm * 128 + m * 16 + ci;
#pragma unroll
      for (int n = 0; n < 4; n++) {
        const int cb = bn0 + wn * 64 + n * 16 + cj;
#pragma unroll
        for (int r = 0; r < 4; r++) {
          float v = acc[m][n][r];
          if constexpr (EPI == 1) {
            v = __expf((v + e0[z * M + rb + r] + e1[z * N + cb] + gam) * (1.f / 1024.f));
            colp[n] += v;
          }
          Cp[(long)(rb + r) * N + cb] = (bf16)v;
        }
      }
    }
    if constexpr (EPI == 1) {
      // lanes l, l^16, l^32, l^48 share column cj across the 4 row-groups;
      // colp already summed the 8 m-frags -> butterfly covers all 128 rows.
#pragma unroll
      for (int n = 0; n < 4; n++) {
        float s = colp[n];
        s += __shfl_xor(s, 16);
        s += __shfl_xor(s, 32);
        if (lane < 16)
          atomicAdd(&e3[(long)z * N + bn0 + wn * 64 + n * 16 + cj], s);
      }
    }
  } else {
    float* Cp = (float*)C;
#pragma unroll
    for (int m = 0; m < 8; m++) {
      const int rb = bm0 + wm * 128 + m * 16 + ci;
#pragma unroll
      for (int n = 0; n < 4; n++) {
        const int cb = bn0 + wn * 64 + n * 16 + cj;
#pragma unroll
        for (int r = 0; r < 4; r++) {
          float v = e0[rb + r] * (acc[m][n][r] + e1[cb]) + e2[cb];
          v = v < 0.f ? 0.01f * v : v;
          Cp[(long)(rb + r) * N + cb] = v;
        }
      }
    }
  }
}

// ---------------- launch ----------------

extern "C" void kernel_launch(void* const* d_in, const int* in_sizes, int n_in,
                              void* d_out, int out_size, void* d_ws, size_t ws_size,
                              hipStream_t stream) {
  const float* xs   = (const float*)d_in[0];
  const float* mask = (const float*)d_in[1];
  const float* Wk   = (const float*)d_in[2];
  const float* bk   = (const float*)d_in[3];
  const float* Wq   = (const float*)d_in[4];
  const float* bq   = (const float*)d_in[5];
  const float* Wv   = (const float*)d_in[6];
  const float* bv   = (const float*)d_in[7];
  const float* Wl   = (const float*)d_in[8];
  const float* bl   = (const float*)d_in[9];
  float* out = (float*)d_out;

  char* ws = (char*)d_ws;
  size_t off = 0;
  auto alloc = [&](size_t bytes) -> void* {
    void* p = ws + off;
    off += (bytes + 255) & ~(size_t)255;
    return p;
  };
  bf16* xs_bf = (bf16*)alloc((size_t)B_ * S_ * DIN_ * 2);   // 32MB
  bf16* t_bf  = (bf16*)alloc((size_t)B_ * S_ * DOUT_ * 2);  // 32MB
  bf16* Wk_bf = (bf16*)alloc((size_t)DIN_ * DOUT_ * 2);
  bf16* Wq_bf = (bf16*)alloc((size_t)DIN_ * DOUT_ * 2);
  bf16* Wv_bf = (bf16*)alloc((size_t)DIN_ * DOUT_ * 2);
  bf16* Wl_t  = (bf16*)alloc((size_t)DIN_ * DOUT_ * 2);
  bf16* Mt    = (bf16*)alloc((size_t)DIN_ * DOUT_ * 2);
  bf16* W2t   = (bf16*)alloc((size_t)DIN_ * DOUT_ * 2);
  float* kb    = (float*)alloc(DIN_ * 4);
  float* qb    = (float*)alloc(DIN_ * 4);
  float* c2    = (float*)alloc(DOUT_ * 4);
  float* gma   = (float*)alloc(256);
  float* alpha = (float*)alloc((size_t)B_ * S_ * 4);
  float* beta  = (float*)alloc((size_t)B_ * S_ * 4);
  float* csum  = (float*)alloc((size_t)B_ * S_ * 4);
  float* rs    = (float*)alloc((size_t)B_ * S_ * 4);
  size_t Eb = (size_t)B_ * S_ * S_ * 2; // 64MB
  bf16* E = (off + Eb <= ws_size) ? (bf16*)alloc(Eb) : (bf16*)d_out; // d_out dead until final GEMM

  // zero the atomic-accumulated buffers first
  hipMemsetAsync(csum, 0, (size_t)B_ * S_ * 4, stream);
  hipMemsetAsync(c2, 0, DOUT_ * 4, stream);

  // casts
  cast_k<<<4096, 256, 0, stream>>>(xs, xs_bf, (long)B_ * S_ * DIN_);
  cast_k<<<1024, 256, 0, stream>>>(Wk, Wk_bf, (long)DIN_ * DOUT_);
  cast_k<<<1024, 256, 0, stream>>>(Wq, Wq_bf, (long)DIN_ * DOUT_);
  cast_k<<<1024, 256, 0, stream>>>(Wv, Wv_bf, (long)DIN_ * DOUT_);
  transpose_cast_k<<<dim3(32, 32), dim3(32, 32), 0, stream>>>(Wl, Wl_t);

  // bias folds (all zero with this data, but computed for correctness)
  rowdot_k<<<256, 256, 0, stream>>>(Wk, bq, kb, DOUT_);
  rowdot_k<<<256, 256, 0, stream>>>(Wq, bk, qb, DOUT_);
  dot1_k<<<1, 256, 0, stream>>>(bk, bq, gma, DOUT_);
  colmat_k<<<dim3(4, 32), 256, 0, stream>>>(Wl, bv, c2);
  alphabeta_k<<<4096, 256, 0, stream>>>(xs, kb, qb, alpha, beta);

  // Mt[e,d] = sum_f Wq[e,f]*Wk[d,f]  (= (Wk Wq^T)^T)
  gemm_bt<<<dim3(8, 8, 1), 256, 0, stream>>>(Wq_bf, Wk_bf, 1024, 1024, 1024, Mt);
  // W2t[e,d] = sum_f Wl_t[e,f]*Wv[d,f] (= (Wv Wl)^T)
  gemm_bt<<<dim3(8, 8, 1), 256, 0, stream>>>(Wl_t, Wv_bf, 1024, 1024, 1024, W2t);
  // t[i,e] = sum_d xs[i,d]*Mt[e,d]
  gemm3<0><<<dim3(4, 64, 1), 512, 0, stream>>>(xs_bf, Mt, B_ * S_, 1024, 1024,
                                               0, 0, 0, t_bf, nullptr, nullptr, nullptr, nullptr);
  // E[b,i,j] = exp((t_i . xs_j + alpha_i + beta_j + gamma)/1024) + fused colsum
  gemm3<1><<<dim3(8, 8, 8), 512, 0, stream>>>(t_bf, xs_bf, S_, S_, 1024,
                                              (long)S_ * DIN_, (long)S_ * DIN_,
                                              (long)S_ * S_, E, alpha, beta, gma, csum);
  // rowsum (w = mask/csum fused inline)
  rowsum_k<<<4096, 256, 0, stream>>>(E, mask, csum, rs);
  // out = leakyrelu(rs_i*(xs_i . W2t_e + c2_e) + bl_e)
  gemm3<2><<<dim3(4, 64, 1), 512, 0, stream>>>(xs_bf, W2t, B_ * S_, 1024, 1024,
                                               0, 0, 0, out, rs, c2, bl, nullptr);
}

// Round 10
// 394.302 us; speedup vs baseline: 1.3447x; 1.0144x over previous
//
#include <hip/hip_runtime.h>

#define B_ 8
#define S_ 2048
#define DIN_ 1024
#define DOUT_ 1024

using bf16 = __bf16;
using bf16x4 = __attribute__((ext_vector_type(4))) bf16;
using bf16x8 = __attribute__((ext_vector_type(8))) bf16;
using f32x4  = __attribute__((ext_vector_type(4))) float;

// ---------------- elementwise / small kernels ----------------

__global__ __launch_bounds__(256) void cast_k(const float* __restrict__ in,
                                              bf16* __restrict__ out, long n) {
  long i = ((long)blockIdx.x * blockDim.x + threadIdx.x) * 4;
  long stride = (long)gridDim.x * blockDim.x * 4;
  for (; i < n; i += stride) {
    float4 v = *(const float4*)(in + i);
    bf16x4 o = { (bf16)v.x, (bf16)v.y, (bf16)v.z, (bf16)v.w };
    *(bf16x4*)(out + i) = o;
  }
}

// Wl [f,e] fp32 -> Wl_t [e,f] bf16  (1024x1024)
__global__ __launch_bounds__(1024) void transpose_cast_k(const float* __restrict__ in,
                                                         bf16* __restrict__ out) {
  __shared__ float tile[32][33];
  int x = blockIdx.x * 32 + threadIdx.x;  // e (input col)
  int y = blockIdx.y * 32 + threadIdx.y;  // f (input row)
  tile[threadIdx.y][threadIdx.x] = in[y * 1024 + x];
  __syncthreads();
  int xo = blockIdx.y * 32 + threadIdx.x; // f (output col)
  int yo = blockIdx.x * 32 + threadIdx.y; // e (output row)
  out[yo * 1024 + xo] = (bf16)tile[threadIdx.x][threadIdx.y];
}

// out[r] = sum_c W[r,c]*v[c]   (one wave per row)
__global__ __launch_bounds__(256) void rowdot_k(const float* __restrict__ W,
                                                const float* __restrict__ v,
                                                float* __restrict__ out, int cols) {
  int row = blockIdx.x * 4 + (threadIdx.x >> 6);
  int lane = threadIdx.x & 63;
  float s = 0.f;
  const float* p = W + (long)row * cols;
  for (int c = lane; c < cols; c += 64) s += p[c] * v[c];
#pragma unroll
  for (int o = 32; o; o >>= 1) s += __shfl_down(s, o);
  if (!lane) out[row] = s;
}

__global__ __launch_bounds__(256) void dot1_k(const float* __restrict__ a,
                                              const float* __restrict__ b,
                                              float* __restrict__ out, int n) {
  __shared__ float sm[256];
  float s = 0.f;
  for (int i = threadIdx.x; i < n; i += 256) s += a[i] * b[i];
  sm[threadIdx.x] = s;
  __syncthreads();
  for (int o = 128; o; o >>= 1) {
    if (threadIdx.x < o) sm[threadIdx.x] += sm[threadIdx.x + o];
    __syncthreads();
  }
  if (!threadIdx.x) out[0] = sm[0];
}

// c2[e] += sum_{f in block} bv[f]*Wl[f,e]   (parallel over f-slices; c2 pre-zeroed)
__global__ __launch_bounds__(256) void colmat_k(const float* __restrict__ Wl,
                                                const float* __restrict__ bv,
                                                float* __restrict__ c2) {
  int e = blockIdx.x * 256 + threadIdx.x;
  int f0 = blockIdx.y * 32;
  float s = 0.f;
#pragma unroll 8
  for (int f = f0; f < f0 + 32; f++) s += bv[f] * Wl[(long)f * 1024 + e];
  atomicAdd(&c2[e], s);
}

// alpha[i] = xs_i . kb ; beta[i] = xs_i . qb ; xs_bf = (bf16)xs  (fused cast)
__global__ __launch_bounds__(256) void alphabeta_k(const float* __restrict__ xs,
                                                   const float* __restrict__ kb,
                                                   const float* __restrict__ qb,
                                                   float* __restrict__ al,
                                                   float* __restrict__ be,
                                                   bf16* __restrict__ xs_bf) {
  int row = blockIdx.x * 4 + (threadIdx.x >> 6);
  int lane = threadIdx.x & 63;
  const float* x = xs + (long)row * DIN_;
  bf16* xo = xs_bf + (long)row * DIN_;
  float sa = 0.f, sb = 0.f;
  for (int c = lane; c < DIN_; c += 64) {
    float xv = x[c];
    xo[c] = (bf16)xv;
    sa += xv * kb[c];
    sb += xv * qb[c];
  }
#pragma unroll
  for (int o = 32; o; o >>= 1) { sa += __shfl_down(sa, o); sb += __shfl_down(sb, o); }
  if (!lane) { al[row] = sa; be[row] = sb; }
}

// rowsum[b,i] = S*EPS + sum_j E[b,i,j]*mask[b,j]/csum[b,j]   (one wave per row)
__global__ __launch_bounds__(256) void rowsum_k(const bf16* __restrict__ E,
                                                const float* __restrict__ mask,
                                                const float* __restrict__ csum,
                                                float* __restrict__ rs) {
  int row = blockIdx.x * 4 + (threadIdx.x >> 6); // global row b*S+i
  int lane = threadIdx.x & 63;
  int b = row >> 11;
  const bf16* p = E + (long)row * S_;
  const float* mb = mask + b * S_;
  const float* cb = csum + b * S_;
  float s = 0.f;
  for (int j = lane * 4; j < S_; j += 256) {
    bf16x4 ev = *(const bf16x4*)(p + j);
    float4 mv = *(const float4*)(mb + j);
    float4 cv = *(const float4*)(cb + j);
    s += (float)ev[0] * mv.x / cv.x + (float)ev[1] * mv.y / cv.y +
         (float)ev[2] * mv.z / cv.z + (float)ev[3] * mv.w / cv.w;
  }
#pragma unroll
  for (int o = 32; o; o >>= 1) s += __shfl_down(s, o);
  if (!lane) rs[row] = s + 2.048e-11f; // S * EPS
}

__device__ __forceinline__ void gld16(const bf16* g, bf16* l) {
  __builtin_amdgcn_global_load_lds(
      (__attribute__((address_space(1))) void*)const_cast<bf16*>(g),
      (__attribute__((address_space(3))) void*)l, 16, 0, 0);
}

// ---------------- small MFMA GEMM (m97 structure), for 1024^3 only ----------
__global__ __launch_bounds__(256) void gemm_bt(
    const bf16* __restrict__ A, const bf16* __restrict__ B,
    int M, int N, int K, void* __restrict__ C) {
  __shared__ __align__(16) bf16 As[128 * 32];
  __shared__ __align__(16) bf16 Bs[128 * 32];
  const int tid = threadIdx.x;
  const int wid = tid >> 6, lane = tid & 63;
  const int bm0 = blockIdx.y * 128, bn0 = blockIdx.x * 128;
  const int mb = (wid >> 1) * 64, nb = (wid & 1) * 64;
  const int fr = lane & 15, ko = (lane >> 4) * 8;

  f32x4 acc[4][4] = {};

  const int srow = wid * 32 + (lane >> 2);
  const int scol = (lane & 3) * 8;
  const bf16* gA = A + (long)(bm0 + srow) * K + scol;
  const bf16* gB = B + (long)(bn0 + srow) * K + scol;
  bf16* lA = As + wid * 32 * 32;
  bf16* lB = Bs + wid * 32 * 32;

  for (int k0 = 0; k0 < K; k0 += 32) {
    gld16(gA + k0, lA);
    gld16(gA + 16 * K + k0, lA + 16 * 32);
    gld16(gB + k0, lB);
    gld16(gB + 16 * K + k0, lB + 16 * 32);
    __syncthreads();
    bf16x8 af[4], bfr[4];
#pragma unroll
    for (int m = 0; m < 4; m++)
      af[m] = *(const bf16x8*)(As + (mb + m * 16 + fr) * 32 + ko);
#pragma unroll
    for (int n = 0; n < 4; n++)
      bfr[n] = *(const bf16x8*)(Bs + (nb + n * 16 + fr) * 32 + ko);
#pragma unroll
    for (int m = 0; m < 4; m++)
#pragma unroll
      for (int n = 0; n < 4; n++)
        acc[m][n] = __builtin_amdgcn_mfma_f32_16x16x32_bf16(af[m], bfr[n], acc[m][n], 0, 0, 0);
    __syncthreads();
  }

  const int ci = (lane >> 4) * 4;
  bf16* Cp = (bf16*)C;
#pragma unroll
  for (int m = 0; m < 4; m++) {
    const int rb = bm0 + mb + m * 16 + ci;
#pragma unroll
    for (int n = 0; n < 4; n++) {
      const int cb = bn0 + nb + n * 16 + fr;
#pragma unroll
      for (int r = 0; r < 4; r++)
        Cp[(long)(rb + r) * N + cb] = (bf16)acc[m][n][r];
    }
  }
}

// ---------------- big MFMA GEMM: C = A[M,K] * B[N,K]^T -----------------------
// BM=256, BN=256, BK=64, 8 waves (2M x 4N), per-wave C = 128x64.
// 2-buffer LDS (128KB). Stage t+1 issued BEFORE compute(t); __syncthreads()
// drains + flips. 8-seg XOR swizzle (conflict-free, verified 0 in r7/r8).
// T1: bijective XCD swizzle of the flattened block id so each XCD gets a
// contiguous chunk of logical tiles (E: one full batch per XCD) -> staging
// loads hit the XCD-private L2 instead of re-fetching HBM. nwg % 8 == 0.
// EPI 0: store bf16 C
// EPI 1: E = exp((acc + e0_i + e1_j + e2[0])/1024), store bf16, colsum -> e3
// EPI 2: out = leakyrelu(e0_i*(acc + e1_j) + e2_j), store fp32

template <int EPI>
__global__ __launch_bounds__(512, 1) void gemm3(
    const bf16* __restrict__ A, const bf16* __restrict__ B,
    int M, int N, int K, long sA, long sB, long sC, void* __restrict__ C,
    const float* __restrict__ e0, const float* __restrict__ e1,
    const float* __restrict__ e2, float* __restrict__ e3) {
  __shared__ __align__(16) bf16 sm[2 * 32768]; // 2 x (A 256x64 + B 256x64) = 128KB
  const int tid = threadIdx.x;
  const int wid = tid >> 6, lane = tid & 63;

  // T1 XCD swizzle (bijective; requires nwg % 8 == 0, true for all launches)
  const int id = blockIdx.x + gridDim.x * (blockIdx.y + gridDim.y * blockIdx.z);
  const int nwg = gridDim.x * gridDim.y * gridDim.z;
  const int swz = (id & 7) * (nwg >> 3) + (id >> 3);
  const int bx = swz % gridDim.x;
  const int tmp = swz / gridDim.x;
  const int by = tmp % gridDim.y;
  const int bz = tmp / gridDim.y;

  A += (long)bz * sA;
  B += (long)bz * sB;
  const int bm0 = by * 256, bn0 = bx * 256;
  const int wm = wid >> 2, wn = wid & 3;   // 2 x 4 waves, per-wave 128x64
  const int NT = K >> 6;

  const int lrow = lane >> 3;            // 0..7
  const int lseg = (lane & 7) ^ lrow;    // pre-swizzled source segment
  const bf16* gA = A + (long)(bm0 + wid * 32 + lrow) * K + lseg * 8;
  const bf16* gB = B + (long)(bn0 + wid * 32 + lrow) * K + lseg * 8;

  f32x4 acc[8][4] = {};

  auto STAGE = [&](int buf, int t) {
    bf16* lA = sm + buf * 32768 + wid * 2048;
    bf16* lB = sm + buf * 32768 + 16384 + wid * 2048;
    const bf16* ga = gA + t * 64;
    const bf16* gb = gB + t * 64;
#pragma unroll
    for (int l = 0; l < 4; l++) gld16(ga + (long)l * 8 * K, lA + l * 512);
#pragma unroll
    for (int l = 0; l < 4; l++) gld16(gb + (long)l * 8 * K, lB + l * 512);
  };

  STAGE(0, 0);
  __syncthreads();   // drain tile0

  const int fr = lane & 15;
  const int seg0 = lane >> 4;            // 0..3

  for (int t = 0; t < NT; ++t) {
    const bf16* Ab = sm + (t & 1) * 32768;
    const bf16* Bb = Ab + 16384;
    if (t + 1 < NT) STAGE((t + 1) & 1, t + 1);  // issue early; hides under compute
#pragma unroll
    for (int kh = 0; kh < 2; kh++) {
      bf16x8 b[4];
#pragma unroll
      for (int n = 0; n < 4; n++) {
        const int row = wn * 64 + n * 16 + fr;
        const int s = (seg0 + 4 * kh) ^ (row & 7);
        b[n] = *(const bf16x8*)(Bb + row * 64 + s * 8);
      }
#pragma unroll
      for (int mh = 0; mh < 2; mh++) {
        bf16x8 a[4];
#pragma unroll
        for (int m = 0; m < 4; m++) {
          const int row = wm * 128 + mh * 64 + m * 16 + fr;
          const int s = (seg0 + 4 * kh) ^ (row & 7);
          a[m] = *(const bf16x8*)(Ab + row * 64 + s * 8);
        }
        __builtin_amdgcn_s_setprio(1);
#pragma unroll
        for (int m = 0; m < 4; m++)
#pragma unroll
          for (int n = 0; n < 4; n++)
            acc[mh * 4 + m][n] = __builtin_amdgcn_mfma_f32_16x16x32_bf16(a[m], b[n], acc[mh * 4 + m][n], 0, 0, 0);
        __builtin_amdgcn_s_setprio(0);
      }
    }
    if (t + 1 < NT) __syncthreads();  // drain t+1's stages + flip buffers
  }

  const int ci = (lane >> 4) * 4;
  const int cj = fr;
  if constexpr (EPI == 0 || EPI == 1) {
    bf16* Cp = (bf16*)C + (long)bz * sC;
    float gam = (EPI == 1) ? e2[0] : 0.f;
    float colp[4] = {0.f, 0.f, 0.f, 0.f};
#pragma unroll
    for (int m = 0; m < 8; m++) {
      const int rb = bm0 + wm * 128 + m * 16 + ci;
#pragma unroll
      for (int n = 0; n < 4; n++) {
        const int cb = bn0 + wn * 64 + n * 16 + cj;
#pragma unroll
        for (int r = 0; r < 4; r++) {
          float v = acc[m][n][r];
          if constexpr (EPI == 1) {
            v = __expf((v + e0[bz * M + rb + r] + e1[bz * N + cb] + gam) * (1.f / 1024.f));
            colp[n] += v;
          }
          Cp[(long)(rb + r) * N + cb] = (bf16)v;
        }
      }
    }
    if constexpr (EPI == 1) {
      // lanes l, l^16, l^32, l^48 share column cj across the 4 row-groups;
      // colp already summed the 8 m-frags -> butterfly covers all 128 rows.
#pragma unroll
      for (int n = 0; n < 4; n++) {
        float s = colp[n];
        s += __shfl_xor(s, 16);
        s += __shfl_xor(s, 32);
        if (lane < 16)
          atomicAdd(&e3[(long)bz * N + bn0 + wn * 64 + n * 16 + cj], s);
      }
    }
  } else {
    float* Cp = (float*)C;
#pragma unroll
    for (int m = 0; m < 8; m++) {
      const int rb = bm0 + wm * 128 + m * 16 + ci;
#pragma unroll
      for (int n = 0; n < 4; n++) {
        const int cb = bn0 + wn * 64 + n * 16 + cj;
#pragma unroll
        for (int r = 0; r < 4; r++) {
          float v = e0[rb + r] * (acc[m][n][r] + e1[cb]) + e2[cb];
          v = v < 0.f ? 0.01f * v : v;
          Cp[(long)(rb + r) * N + cb] = v;
        }
      }
    }
  }
}

// ---------------- launch ----------------

extern "C" void kernel_launch(void* const* d_in, const int* in_sizes, int n_in,
                              void* d_out, int out_size, void* d_ws, size_t ws_size,
                              hipStream_t stream) {
  const float* xs   = (const float*)d_in[0];
  const float* mask = (const float*)d_in[1];
  const float* Wk   = (const float*)d_in[2];
  const float* bk   = (const float*)d_in[3];
  const float* Wq   = (const float*)d_in[4];
  const float* bq   = (const float*)d_in[5];
  const float* Wv   = (const float*)d_in[6];
  const float* bv   = (const float*)d_in[7];
  const float* Wl   = (const float*)d_in[8];
  const float* bl   = (const float*)d_in[9];
  float* out = (float*)d_out;

  char* ws = (char*)d_ws;
  size_t off = 0;
  auto alloc = [&](size_t bytes) -> void* {
    void* p = ws + off;
    off += (bytes + 255) & ~(size_t)255;
    return p;
  };
  bf16* xs_bf = (bf16*)alloc((size_t)B_ * S_ * DIN_ * 2);   // 32MB
  bf16* t_bf  = (bf16*)alloc((size_t)B_ * S_ * DOUT_ * 2);  // 32MB
  bf16* Wk_bf = (bf16*)alloc((size_t)DIN_ * DOUT_ * 2);
  bf16* Wq_bf = (bf16*)alloc((size_t)DIN_ * DOUT_ * 2);
  bf16* Wv_bf = (bf16*)alloc((size_t)DIN_ * DOUT_ * 2);
  bf16* Wl_t  = (bf16*)alloc((size_t)DIN_ * DOUT_ * 2);
  bf16* Mt    = (bf16*)alloc((size_t)DIN_ * DOUT_ * 2);
  bf16* W2t   = (bf16*)alloc((size_t)DIN_ * DOUT_ * 2);
  float* kb    = (float*)alloc(DIN_ * 4);
  float* qb    = (float*)alloc(DIN_ * 4);
  float* c2    = (float*)alloc(DOUT_ * 4);
  float* gma   = (float*)alloc(256);
  float* alpha = (float*)alloc((size_t)B_ * S_ * 4);
  float* beta  = (float*)alloc((size_t)B_ * S_ * 4);
  float* csum  = (float*)alloc((size_t)B_ * S_ * 4);
  float* rs    = (float*)alloc((size_t)B_ * S_ * 4);
  size_t Eb = (size_t)B_ * S_ * S_ * 2; // 64MB
  bf16* E = (off + Eb <= ws_size) ? (bf16*)alloc(Eb) : (bf16*)d_out; // d_out dead until final GEMM

  // zero the atomic-accumulated buffers first
  hipMemsetAsync(csum, 0, (size_t)B_ * S_ * 4, stream);
  hipMemsetAsync(c2, 0, DOUT_ * 4, stream);

  // casts (xs cast is fused into alphabeta_k)
  cast_k<<<1024, 256, 0, stream>>>(Wk, Wk_bf, (long)DIN_ * DOUT_);
  cast_k<<<1024, 256, 0, stream>>>(Wq, Wq_bf, (long)DIN_ * DOUT_);
  cast_k<<<1024, 256, 0, stream>>>(Wv, Wv_bf, (long)DIN_ * DOUT_);
  transpose_cast_k<<<dim3(32, 32), dim3(32, 32), 0, stream>>>(Wl, Wl_t);

  // bias folds (all zero with this data, but computed for correctness)
  rowdot_k<<<256, 256, 0, stream>>>(Wk, bq, kb, DOUT_);
  rowdot_k<<<256, 256, 0, stream>>>(Wq, bk, qb, DOUT_);
  dot1_k<<<1, 256, 0, stream>>>(bk, bq, gma, DOUT_);
  colmat_k<<<dim3(4, 32), 256, 0, stream>>>(Wl, bv, c2);
  // alpha/beta + fused xs->bf16 cast
  alphabeta_k<<<4096, 256, 0, stream>>>(xs, kb, qb, alpha, beta, xs_bf);

  // Mt[e,d] = sum_f Wq[e,f]*Wk[d,f]  (= (Wk Wq^T)^T)
  gemm_bt<<<dim3(8, 8, 1), 256, 0, stream>>>(Wq_bf, Wk_bf, 1024, 1024, 1024, Mt);
  // W2t[e,d] = sum_f Wl_t[e,f]*Wv[d,f] (= (Wv Wl)^T)
  gemm_bt<<<dim3(8, 8, 1), 256, 0, stream>>>(Wl_t, Wv_bf, 1024, 1024, 1024, W2t);
  // t[i,e] = sum_d xs[i,d]*Mt[e,d]
  gemm3<0><<<dim3(4, 64, 1), 512, 0, stream>>>(xs_bf, Mt, B_ * S_, 1024, 1024,
                                               0, 0, 0, t_bf, nullptr, nullptr, nullptr, nullptr);
  // E[b,i,j] = exp((t_i . xs_j + alpha_i + beta_j + gamma)/1024) + fused colsum
  gemm3<1><<<dim3(8, 8, 8), 512, 0, stream>>>(t_bf, xs_bf, S_, S_, 1024,
                                              (long)S_ * DIN_, (long)S_ * DIN_,
                                              (long)S_ * S_, E, alpha, beta, gma, csum);
  // rowsum (w = mask/csum fused inline)
  rowsum_k<<<4096, 256, 0, stream>>>(E, mask, csum, rs);
  // out = leakyrelu(rs_i*(xs_i . W2t_e + c2_e) + bl_e)
  gemm3<2><<<dim3(4, 64, 1), 512, 0, stream>>>(xs_bf, W2t, B_ * S_, 1024, 1024,
                                               0, 0, 0, out, rs, c2, bl, nullptr);
}